// Round 7
// baseline (252.353 us; speedup 1.0000x reference)
//
#include <hip/hip_runtime.h>
#include <hip/hip_bf16.h>
#include <stdint.h>

// Problem constants
#define H_    16
#define N_    2048
#define DIM_  1024
#define DH_   64
#define NN_   2
#define J_    2050     // N + NNULL
#define JP_   2112     // 33*64, padded j (Kb zero tail via vtransp, VTp zero-filled)
#define B_    2
#define M_    4096     // B * N
#define QT2_  16       // 128-row q-tiles
#define NSEG2_ 39      // sum over qt2 of ceil((2*qt2+3)/9)
#define SLOT2_ 8448    // u16s per partial slot: 128*64 O + 256 (=128 fp32 l)

#define S8L_  11.541560327111707f   // 8 * log2(e), folded into Qn at Q-GEMM epilogue
#define LOG2E_ 1.4426950408889634f

typedef unsigned short u16;
typedef unsigned int u32;
typedef short bf16x8 __attribute__((ext_vector_type(8)));
typedef float f32x4 __attribute__((ext_vector_type(4)));

__device__ __forceinline__ u16 f2b(float f) {
  union { float f; unsigned int i; } v; v.f = f;
  unsigned int r = v.i + 0x7fffu + ((v.i >> 16) & 1u);   // RNE
  return (u16)(r >> 16);
}
__device__ __forceinline__ float lo2f(u32 u) {
  union { u32 i; float f; } v; v.i = u << 16; return v.f;
}
__device__ __forceinline__ float hi2f(u32 u) {
  union { u32 i; float f; } v; v.i = u & 0xffff0000u; return v.f;
}
__device__ __forceinline__ void unp8(const uint4 u, float* d) {
  d[0] = lo2f(u.x); d[1] = hi2f(u.x); d[2] = lo2f(u.y); d[3] = hi2f(u.y);
  d[4] = lo2f(u.z); d[5] = hi2f(u.z); d[6] = lo2f(u.w); d[7] = hi2f(u.w);
}
// packed fp32x2 -> bf16x2 (single v_cvt_pk_bf16_f32)
__device__ __forceinline__ u32 pk2(float a, float b) {
  union { __hip_bfloat162 h; u32 u; } x;
  x.h = __float22bfloat162_rn(make_float2(a, b));
  return x.u;
}
// async global->LDS DMA, 16B/lane; LDS dest = wave-uniform base + lane*16
__device__ __forceinline__ void dma16(const u16* g, u16* l) {
  __builtin_amdgcn_global_load_lds(
      (const __attribute__((address_space(1))) u32*)(const void*)g,
      (__attribute__((address_space(3))) u32*)(void*)l, 16, 0, 0);
}

// ------------- fused transpose + cast of the 3 weight matrices -------------
// Wq (1024x1024), Wkv (1024x2048), Wout (1024x1024); fp32 RxC -> bf16 CxR
__global__ __launch_bounds__(256) void ktranspose3(const float* __restrict__ Wq,
                                                   const float* __restrict__ Wkv,
                                                   const float* __restrict__ Wout,
                                                   u16* __restrict__ WqT,
                                                   u16* __restrict__ WkvT,
                                                   u16* __restrict__ WoutT) {
  __shared__ float tile[32][33];
  int bx = blockIdx.x;
  const float* in; u16* out; int C; int cx;
  if (bx < 32)      { in = Wq;   out = WqT;   C = 1024; cx = bx; }
  else if (bx < 96) { in = Wkv;  out = WkvT;  C = 2048; cx = bx - 32; }
  else              { in = Wout; out = WoutT; C = 1024; cx = bx - 96; }
  const int R = 1024;
  int tx = threadIdx.x & 31, ty = threadIdx.x >> 5;   // 32 x 8
  int c0 = cx * 32, r0 = blockIdx.y * 32;
  #pragma unroll
  for (int i = 0; i < 32; i += 8)
    tile[ty + i][tx] = in[(size_t)(r0 + ty + i) * C + c0 + tx];
  __syncthreads();
  #pragma unroll
  for (int i = 0; i < 32; i += 8)
    out[(size_t)(c0 + ty + i) * R + r0 + tx] = f2b(tile[tx][ty + i]);
}

// ---------- LayerNorm (fp32 in) -> xn (bf16 LN) + xbf (bf16 cast of x) ----------
__global__ __launch_bounds__(256) void lnorm_k(const float* __restrict__ x,
                                               const float* __restrict__ g,
                                               const float* __restrict__ bb,
                                               u16* __restrict__ xn,
                                               u16* __restrict__ xbf) {
  int row = blockIdx.x;
  int t = threadIdx.x;
  float4 rw = *(const float4*)(x + (size_t)row * DIM_ + t * 4);
  float v0 = rw.x, v1 = rw.y, v2 = rw.z, v3 = rw.w;
  uint2 cw;
  cw.x = pk2(v0, v1);
  cw.y = pk2(v2, v3);
  *(uint2*)(xbf + (size_t)row * DIM_ + t * 4) = cw;
  float s = v0 + v1 + v2 + v3;
  float ss = v0 * v0 + v1 * v1 + v2 * v2 + v3 * v3;
  #pragma unroll
  for (int o = 32; o; o >>= 1) { s += __shfl_xor(s, o, 64); ss += __shfl_xor(ss, o, 64); }
  __shared__ float red[8];
  int lane = t & 63, w = t >> 6;
  if (lane == 0) { red[w] = s; red[4 + w] = ss; }
  __syncthreads();
  float S = red[0] + red[1] + red[2] + red[3];
  float SS = red[4] + red[5] + red[6] + red[7];
  float mu = S * (1.0f / DIM_);
  float var = SS * (1.0f / DIM_) - mu * mu;
  float rs = rsqrtf(var + 1e-5f);
  float4 gv = *(const float4*)(g + t * 4);
  float4 bv = *(const float4*)(bb + t * 4);
  uint2 ow;
  ow.x = pk2((v0 - mu) * rs * gv.x + bv.x, (v1 - mu) * rs * gv.y + bv.y);
  ow.y = pk2((v2 - mu) * rs * gv.z + bv.z, (v3 - mu) * rs * gv.w + bv.w);
  *(uint2*)(xn + (size_t)row * DIM_ + t * 4) = ow;
}

// ---------------- MFMA GEMM, 128m x 64n tile, BK=64, swizzled LDS ----------------
// R4: XCD y-chunk swizzle + 2-phase double-buffered K-loop (see R4 notes).
// LDS slot for (row, kblk of 8 u16): row*64 + ((kblk ^ (row&7)) * 8)  -> conflict-free b128
// MODE 1: fp32 row-major -> dst0
// MODE 2: per-row l2norm over 64-col head * qs * 8*log2e -> Qn (b,h,n,d)
// MODE 3: cols<1024: l2norm*ks -> Kb (stride JP); else bf16 -> Vb (stride J)
template <int MODE>
__global__ __launch_bounds__(256) void gemm_k(const u16* __restrict__ A,
                                              const u16* __restrict__ BT,
                                              void* __restrict__ dst0,
                                              void* __restrict__ dst1,
                                              const float* __restrict__ scale,
                                              int M, int Nc, int K) {
  __shared__ u16 As[2][128 * 64];   // 32 KB
  __shared__ u16 Bs[2][64 * 64];    // 16 KB
  int tid = threadIdx.x, wv = tid >> 6, lane = tid & 63;
  int fm = lane & 15, fg = lane >> 4;
  // ---- bijective XCD y-chunk remap (gy=32=8*4, nwg%8==0 for all call sites) ----
  int nlin = (int)blockIdx.x + (int)gridDim.x * (int)blockIdx.y;
  int gx = (int)gridDim.x;
  int ypc = (int)gridDim.y >> 3;           // row-panels per XCD (=4)
  int mm = nlin >> 3;
  int row0 = ((nlin & 7) * ypc + mm / gx) * 128;
  int col0 = (mm % gx) * 64;
  f32x4 acc[2][4] = {};
  // staging geometry: one dma16 = 8 rows x 128B; lane i -> row i>>3, stored kblk i&7
  int srow = lane >> 3;                 // 0..7
  int skb = ((lane & 7) ^ srow) * 8;    // swizzled global k-offset (u16)
  const u16* Ag = A + (size_t)(row0 + wv * 32 + srow) * K + skb;
  const u16* Bg = BT + (size_t)(col0 + wv * 16 + srow) * K + skb;
  // frag read offsets (row&7 == fm&7 since row = mult16 + fm)
  int fr7 = fm & 7;
  int ak0 = (fg ^ fr7) * 8;            // k-half 0: kblk = fg
  int ak1 = ((fg + 4) ^ fr7) * 8;      // k-half 1: kblk = fg + 4
  // ---- prologue: stage k0=0 into buffer 0 ----
  {
    u16* AsW = As[0] + (wv * 32) * 64;
    u16* BsW = Bs[0] + (wv * 16) * 64;
    dma16(Ag,                    AsW);
    dma16(Ag + (size_t)8 * K,    AsW + 8 * 64);
    dma16(Ag + (size_t)16 * K,   AsW + 16 * 64);
    dma16(Ag + (size_t)24 * K,   AsW + 24 * 64);
    dma16(Bg,                    BsW);
    dma16(Bg + (size_t)8 * K,    BsW + 8 * 64);
  }
  __syncthreads();
  int cur = 0;
  for (int k0 = 0; k0 < K; k0 += 64) {
    // prefetch next K-step into the other buffer (fire-and-forget)
    if (k0 + 64 < K) {
      int kn = k0 + 64;
      u16* AsW = As[cur ^ 1] + (wv * 32) * 64;
      u16* BsW = Bs[cur ^ 1] + (wv * 16) * 64;
      dma16(Ag + kn,                    AsW);
      dma16(Ag + (size_t)8 * K + kn,    AsW + 8 * 64);
      dma16(Ag + (size_t)16 * K + kn,   AsW + 16 * 64);
      dma16(Ag + (size_t)24 * K + kn,   AsW + 24 * 64);
      dma16(Bg + kn,                    BsW);
      dma16(Bg + (size_t)8 * K + kn,    BsW + 8 * 64);
    }
    // compute current buffer
    bf16x8 af0[2], af1[2], bf0[4], bf1[4];
    #pragma unroll
    for (int mt = 0; mt < 2; mt++) {
      int rbase = (wv * 32 + mt * 16 + fm) * 64;
      af0[mt] = *(const bf16x8*)&As[cur][rbase + ak0];
      af1[mt] = *(const bf16x8*)&As[cur][rbase + ak1];
    }
    #pragma unroll
    for (int nt = 0; nt < 4; nt++) {
      int rbase = (nt * 16 + fm) * 64;
      bf0[nt] = *(const bf16x8*)&Bs[cur][rbase + ak0];
      bf1[nt] = *(const bf16x8*)&Bs[cur][rbase + ak1];
    }
    #pragma unroll
    for (int mt = 0; mt < 2; mt++)
      #pragma unroll
      for (int nt = 0; nt < 4; nt++) {
        acc[mt][nt] = __builtin_amdgcn_mfma_f32_16x16x32_bf16(af0[mt], bf0[nt], acc[mt][nt], 0, 0, 0);
        acc[mt][nt] = __builtin_amdgcn_mfma_f32_16x16x32_bf16(af1[mt], bf1[nt], acc[mt][nt], 0, 0, 0);
      }
    __syncthreads();
    cur ^= 1;
  }
  // C/D layout per 16x16 tile: col = fm, row = fg*4 + r
  if (MODE == 1) {
    float* C = (float*)dst0;
    #pragma unroll
    for (int mt = 0; mt < 2; mt++)
      #pragma unroll
      for (int r = 0; r < 4; r++) {
        int m = row0 + wv * 32 + mt * 16 + fg * 4 + r;
        #pragma unroll
        for (int nt = 0; nt < 4; nt++)
          C[(size_t)m * Nc + col0 + nt * 16 + fm] = acc[mt][nt][r];
      }
  } else {
    bool isK = (MODE == 2) || (col0 < 1024);
    int h = (isK ? col0 : col0 - 1024) >> 6;
    float sv[4];
    if (isK) {
      #pragma unroll
      for (int nt = 0; nt < 4; nt++) sv[nt] = scale[nt * 16 + fm];
      if (MODE == 2) {
        #pragma unroll
        for (int nt = 0; nt < 4; nt++) sv[nt] *= S8L_;
      }
    }
    u16* Do = (u16*)((MODE == 3 && !isK) ? dst1 : dst0);
    #pragma unroll
    for (int mt = 0; mt < 2; mt++) {
      #pragma unroll
      for (int r = 0; r < 4; r++) {
        float inv = 1.0f;
        if (isK) {
          float ssp = 0.0f;
          #pragma unroll
          for (int nt = 0; nt < 4; nt++) ssp += acc[mt][nt][r] * acc[mt][nt][r];
          #pragma unroll
          for (int o = 1; o <= 8; o <<= 1) ssp += __shfl_xor(ssp, o, 64);
          inv = 1.0f / fmaxf(sqrtf(ssp), 1e-12f);
        }
        int m = row0 + wv * 32 + mt * 16 + fg * 4 + r;
        int b = m >> 11, n = m & 2047;
        size_t base;
        if (MODE == 2)      base = (((size_t)(b * H_ + h)) * N_ + n) * 64;
        else if (isK)       base = (((size_t)(b * H_ + h)) * JP_ + (n + NN_)) * 64;
        else                base = (((size_t)(b * H_ + h)) * J_ + (n + NN_)) * 64;
        #pragma unroll
        for (int nt = 0; nt < 4; nt++) {
          float val = acc[mt][nt][r];
          if (isK) val = val * inv * sv[nt];
          Do[base + nt * 16 + fm] = f2b(val);
        }
      }
    }
  }
}

// ------- V transpose+permute: Vb (b,h,j,d) + null kv -> VTp (b,h,d,pos); also Kb j<2 -------
// Also zero-fills Kb tail rows j in [J_, JP_).
__global__ __launch_bounds__(256) void vtransp_k(const u16* __restrict__ Vb,
                                                 const float* __restrict__ nkv,
                                                 const float* __restrict__ ks,
                                                 u16* __restrict__ Kb,
                                                 u16* __restrict__ VTp) {
  __shared__ u16 tile[64][80];
  int t = threadIdx.x;
  int c = blockIdx.x, bh = blockIdx.y, h = bh & 15;
  int jl = t >> 2, dc = (t & 3) * 16;
  int j = c * 64 + jl;
  if (j < NN_) {
    float kvv[16];
    float kssp = 0.0f;
    #pragma unroll
    for (int e = 0; e < 16; e++) {
      float vv = nkv[(size_t)(h * 4 + 2 * j + 1) * 64 + dc + e];
      tile[jl][dc + e] = f2b(vv);
      float kv = nkv[(size_t)(h * 4 + 2 * j) * 64 + dc + e];
      kvv[e] = kv; kssp += kv * kv;
    }
    kssp += __shfl_xor(kssp, 1, 64);
    kssp += __shfl_xor(kssp, 2, 64);
    float inv = 1.0f / fmaxf(sqrtf(kssp), 1e-12f);
    #pragma unroll
    for (int e = 0; e < 16; e++)
      Kb[((size_t)bh * JP_ + j) * 64 + dc + e] = f2b(kvv[e] * inv * ks[dc + e]);
  } else if (j < J_) {
    const uint4* src = (const uint4*)(Vb + ((size_t)bh * J_ + j) * 64 + dc);
    *(uint4*)&tile[jl][dc] = src[0];
    *(uint4*)&tile[jl][dc + 8] = src[1];
  } else {
    uint4 z = {0, 0, 0, 0};
    *(uint4*)&tile[jl][dc] = z;
    *(uint4*)&tile[jl][dc + 8] = z;
    uint4* kd = (uint4*)(Kb + ((size_t)bh * JP_ + j) * 64 + dc);
    kd[0] = z;
    kd[1] = z;
  }
  __syncthreads();
  int d = t >> 2, p0 = (t & 3) * 16;
  u16 tmp[16] __attribute__((aligned(16)));
  #pragma unroll
  for (int e = 0; e < 16; e++) {
    int pos = p0 + e;
    int h2 = pos >> 5, rem = pos & 31;
    int fgp = rem >> 3, tt = rem & 7;
    int nt = tt >> 2, r = tt & 3;
    int jloc = (h2 * 2 + nt) * 16 + fgp * 4 + r;
    tmp[e] = tile[jloc][d];
  }
  uint4* dstp = (uint4*)(VTp + ((size_t)bh * 64 + d) * JP_ + c * 64 + p0);
  dstp[0] = ((uint4*)tmp)[0];
  dstp[1] = ((uint4*)tmp)[1];
}

// per-mt softmax: 16 scores -> 16 bf16 P values (8 packed words), lp accumulate
#define SOFTMAX16(ACCS, BSTART, FULLVIS, THR, LP, PW)                                \
  {                                                                                  \
    float bnt = (BSTART);                                                            \
    float lps = 0.0f;                                                                \
    if (FULLVIS) {                                                                   \
      _Pragma("unroll")                                                              \
      for (int nt = 0; nt < 4; nt++) {                                               \
        float e0 = __builtin_amdgcn_exp2f(ACCS[nt][0] + bnt);                        \
        float e1 = __builtin_amdgcn_exp2f((ACCS[nt][1] + sr1) + bnt);                \
        float e2 = __builtin_amdgcn_exp2f((ACCS[nt][2] + sr2) + bnt);                \
        float e3 = __builtin_amdgcn_exp2f((ACCS[nt][3] + sr3) + bnt);                \
        PW[nt * 2] = pk2(e0, e1);                                                    \
        PW[nt * 2 + 1] = pk2(e2, e3);                                                \
        lps += (e0 + e1) + (e2 + e3);                                                \
        bnt += s16;                                                                  \
      }                                                                              \
    } else {                                                                         \
      _Pragma("unroll")                                                              \
      for (int nt = 0; nt < 4; nt++) {                                               \
        int ib = nt * 16 + fg4;                                                      \
        float e0 = __builtin_amdgcn_exp2f(ACCS[nt][0] + bnt);                        \
        float e1 = __builtin_amdgcn_exp2f((ACCS[nt][1] + sr1) + bnt);                \
        float e2 = __builtin_amdgcn_exp2f((ACCS[nt][2] + sr2) + bnt);                \
        float e3 = __builtin_amdgcn_exp2f((ACCS[nt][3] + sr3) + bnt);                \
        e0 = (ib + 0 <= (THR)) ? e0 : 0.0f;                                          \
        e1 = (ib + 1 <= (THR)) ? e1 : 0.0f;                                          \
        e2 = (ib + 2 <= (THR)) ? e2 : 0.0f;                                          \
        e3 = (ib + 3 <= (THR)) ? e3 : 0.0f;                                          \
        PW[nt * 2] = pk2(e0, e1);                                                    \
        PW[nt * 2 + 1] = pk2(e2, e3);                                                \
        lps += (e0 + e1) + (e2 + e3);                                                \
        bnt += s16;                                                                  \
      }                                                                              \
    }                                                                                \
    LP += lps;                                                                       \
  }

// ---------------- MFMA flash attention, 128-row q-tiles, DOUBLE-BUFFERED -----
// R6: R5 body + 2-phase double-buffer. R2's dbuf failed because at grid 10.5
//   blocks/CU, LDS 16->32KB halved residency. R5's grid is 4.9 blocks/CU and
//   32KB LDS still fits 5 blocks/CU -> dbuf is now occupancy-free. Compute per
//   chunk also doubled (32 MFMA + 2 softmax ~ 500-700cyc), so the prefetch
//   issued at the top of the body fully covers L2-resident K/V latency
//   (~200-400cyc; K/V L2-resident per XCD since R3's swizzle, FETCH=13MB).
//   Per-chunk cost: ~1500cyc (serial drain) -> ~compute+barrier.
// Prefetch is issued by ALL waves before the masked-chunk skip (DMA must land
//   regardless of whether this wave computes).
// Segments: 9 chunks each; NSEG2_=39/bh; grid 39x32=1248=8*156 (XCD remap bijective:
//   xcd=n&7, m=n>>3, bh=xcd*4+m/39, segid=m%39).
__global__ __launch_bounds__(256, 5) void attn_k(const u16* __restrict__ Qn,
                                                 const u16* __restrict__ Kb,
                                                 const u16* __restrict__ VTp,
                                                 const float* __restrict__ qs,
                                                 const float* __restrict__ ks,
                                                 u16* __restrict__ partials) {
  __shared__ u16 Ks0[2][64 * 32], Ks1[2][64 * 32];   // K chunk rows j, d 0..31 / 32..63
  __shared__ u16 Vs0[2][64 * 32], Vs1[2][64 * 32];   // V^T chunk rows d, j-pos 0..31 / 32..63
  int tid = threadIdx.x;
  int wv = tid >> 6, lane = tid & 63;
  int fm = lane & 15, fg = lane >> 4;
  int fg4 = fg * 4;
  // ---- T1 bijective XCD remap ----
  int n = (int)blockIdx.x + NSEG2_ * (int)blockIdx.y;  // hw linear id (x-major)
  int m = n >> 3;                                      // 0..155
  int bh = (n & 7) * 4 + m / NSEG2_;                   // 4 bh per XCD
  int segid = m % NSEG2_;
  int h = bh & 15;
  // segment decode (qt2 descending)
  int cum = 0, qt2 = 0, seg = 0;
  #pragma unroll 1
  for (int i = 0; i < 16; i++) {
    int t = 15 - i, s = (2 * t + 11) / 9;
    if (segid < cum + s) { qt2 = t; seg = segid - cum; break; }
    cum += s;
  }
  int q0 = qt2 * 128;
  int qw = q0 + wv * 32;          // wave's first row (mt=0, fm=0)
  int qr = qw + fm;               // lane's mt=0 row
  float slope = exp2f(-0.5f * (float)(h + 1));
  float prod = fabsf(qs[lane] * ks[lane]);
  #pragma unroll
  for (int o = 32; o; o >>= 1) prod = fmaxf(prod, __shfl_xor(prod, o, 64));
  float MbL = 8.0f * prod * LOG2E_;          // max-bound, log2 domain
  float slopeL = slope * LOG2E_;
  // Q frags: mt0 row qr, mt1 row qr+16
  const u16* qp = Qn + ((size_t)bh * N_ + qr) * 64 + fg * 8;
  bf16x8 qa0 = *(const bf16x8*)(qp);
  bf16x8 qa1 = *(const bf16x8*)(qp + 32);
  bf16x8 qb0 = *(const bf16x8*)(qp + 16 * 64);
  bf16x8 qb1 = *(const bf16x8*)(qp + 16 * 64 + 32);
  f32x4 accO[2][4] = {};
  float lp0 = 0.0f, lp1 = 0.0f;
  int lr = lane >> 2;                                  // staging row 0..15
  int kbs = ((lane & 3) ^ ((lane >> 3) & 3)) * 8;      // swizzled staging k-offset
  int fs = (fg ^ ((fm >> 1) & 3)) * 8;                 // swizzled frag offset
  const u16* KbBH = Kb + (size_t)bh * JP_ * 64;
  const u16* VTbh = VTp + (size_t)bh * 64 * JP_;
  int c0 = seg * 9;
  int c1 = min(c0 + 9, 2 * qt2 + 3);
  // bias ladder (mt0): bias0 at (chunk c0, nt=0, r=0): slopeL*(jj - qr - 2) - MbL
  float bias0 = slopeL * (float)(c0 * 64 + fg4 - qr - 2) - MbL;
  float sr1 = slopeL, sr2 = slopeL * 2.0f, sr3 = slopeL * 3.0f;
  float s16 = slopeL * 16.0f;
  float d64 = slopeL * 64.0f;
  // stage chunk c into buffer buf (all waves; 4 dma16)
  auto stage = [&](int c, int buf) {
    int jb = c * 64;
    const u16* Kg = KbBH + (size_t)(jb + wv * 16 + lr) * 64 + kbs;
    dma16(Kg,      Ks0[buf] + wv * 512);
    dma16(Kg + 32, Ks1[buf] + wv * 512);
    const u16* Vg = VTbh + (size_t)(wv * 16 + lr) * JP_ + jb + kbs;
    dma16(Vg,      Vs0[buf] + wv * 512);
    dma16(Vg + 32, Vs1[buf] + wv * 512);
  };
  // ---- prologue ----
  stage(c0, 0);
  __syncthreads();
  int cur = 0;
  for (int c = c0; c < c1; c++) {
    // prefetch next chunk into other buffer (fire-and-forget; before any skip)
    if (c + 1 < c1) stage(c + 1, cur ^ 1);
    int jb = c * 64;
    // whole-chunk skip if all 32 wave rows are masked (wave max row qw+31)
    if (jb <= qw + 33) {
      // S^T = K Q^T, both mt share K fragments (Qn pre-scaled by 8*log2e)
      f32x4 accS0[4] = {}, accS1[4] = {};
      #pragma unroll
      for (int nt = 0; nt < 4; nt++) {
        bf16x8 kf0 = *(const bf16x8*)&Ks0[cur][(nt * 16 + fm) * 32 + fs];
        accS0[nt] = __builtin_amdgcn_mfma_f32_16x16x32_bf16(kf0, qa0, accS0[nt], 0, 0, 0);
        accS1[nt] = __builtin_amdgcn_mfma_f32_16x16x32_bf16(kf0, qb0, accS1[nt], 0, 0, 0);
        bf16x8 kf1 = *(const bf16x8*)&Ks1[cur][(nt * 16 + fm) * 32 + fs];
        accS0[nt] = __builtin_amdgcn_mfma_f32_16x16x32_bf16(kf1, qa1, accS0[nt], 0, 0, 0);
        accS1[nt] = __builtin_amdgcn_mfma_f32_16x16x32_bf16(kf1, qb1, accS1[nt], 0, 0, 0);
      }
      // softmax per mt
      union { bf16x8 v[2]; u32 u[8]; } PA, PB;
      bool fv0 = (jb + 61 <= qw);
      bool fv1 = (jb + 61 <= qw + 16);
      int thr0 = qr + 2 - jb;
      SOFTMAX16(accS0, bias0, fv0, thr0, lp0, PA.u);
      SOFTMAX16(accS1, bias0 - s16, fv1, thr0 + 16, lp1, PB.u);
      // O^T += V^T P^T, both mt share V fragments
      #pragma unroll
      for (int nt = 0; nt < 4; nt++) {
        bf16x8 vf0 = *(const bf16x8*)&Vs0[cur][(nt * 16 + fm) * 32 + fs];
        accO[0][nt] = __builtin_amdgcn_mfma_f32_16x16x32_bf16(vf0, PA.v[0], accO[0][nt], 0, 0, 0);
        accO[1][nt] = __builtin_amdgcn_mfma_f32_16x16x32_bf16(vf0, PB.v[0], accO[1][nt], 0, 0, 0);
        bf16x8 vf1 = *(const bf16x8*)&Vs1[cur][(nt * 16 + fm) * 32 + fs];
        accO[0][nt] = __builtin_amdgcn_mfma_f32_16x16x32_bf16(vf1, PA.v[1], accO[0][nt], 0, 0, 0);
        accO[1][nt] = __builtin_amdgcn_mfma_f32_16x16x32_bf16(vf1, PB.v[1], accO[1][nt], 0, 0, 0);
      }
    }
    bias0 += d64;
    // one barrier per chunk: drains prefetch (vmcnt(0)) for next iter's compute
    // AND guards buf[cur] against re-staging before all waves finished reading.
    __syncthreads();
    cur ^= 1;
  }
  lp0 += __shfl_xor(lp0, 16, 64);
  lp0 += __shfl_xor(lp0, 32, 64);
  lp1 += __shfl_xor(lp1, 16, 64);
  lp1 += __shfl_xor(lp1, 32, 64);
  // slot: [q 128][d 64] bf16 + l fp32[128]
  u16* P = partials + ((size_t)bh * NSEG2_ + segid) * SLOT2_;
  #pragma unroll
  for (int mt = 0; mt < 2; mt++) {
    int sq = wv * 32 + mt * 16 + fm;
    #pragma unroll
    for (int nt = 0; nt < 4; nt++) {
      uint2 ow;
      ow.x = pk2(accO[mt][nt][0], accO[mt][nt][1]);
      ow.y = pk2(accO[mt][nt][2], accO[mt][nt][3]);
      *(uint2*)(P + sq * 64 + nt * 16 + fg4) = ow;
    }
    if (fg == 0) *(float*)(P + 8192 + 2 * sq) = (mt == 0) ? lp0 : lp1;
  }
}

// ---------------- combine partials -> AO (b,n,h,d), 128-row tiles ----------------
__global__ __launch_bounds__(256) void comb_k(const u16* __restrict__ partials,
                                              u16* __restrict__ AO) {
  int qt2 = blockIdx.x, bh = blockIdx.y, b = bh >> 4, h = bh & 15;
  int t = threadIdx.x, q = t >> 1, dh = (t & 1) * 32;
  int s = (2 * qt2 + 11) / 9;
  int cum = 0;
  for (int tt = qt2 + 1; tt < 16; tt++) cum += (2 * tt + 11) / 9;
  float acc[32] = {};
  float lsum = 0.0f;
  for (int k = 0; k < s; k++) {
    const u16* P = partials + ((size_t)bh * NSEG2_ + cum + k) * SLOT2_;
    float tmp[8];
    #pragma unroll
    for (int w = 0; w < 4; w++) {
      uint4 a = *(const uint4*)(P + q * 64 + dh + w * 8);
      unp8(a, tmp);
      #pragma unroll
      for (int e = 0; e < 8; e++) acc[w * 8 + e] += tmp[e];
    }
    lsum += *(const float*)(P + 8192 + 2 * q);
  }
  float linv = 1.0f / lsum;
  int nrow = qt2 * 128 + q;
  u16* dst = AO + (((size_t)(b * N_ + nrow)) * H_ + h) * 64 + dh;
  u16 ov[32] __attribute__((aligned(16)));
  #pragma unroll
  for (int e = 0; e < 32; e++) ov[e] = f2b(acc[e] * linv);
  #pragma unroll
  for (int w = 0; w < 4; w++)
    *(uint4*)(dst + w * 8) = ((uint4*)ov)[w];
}

// ---------------- launch ----------------
extern "C" void kernel_launch(void* const* d_in, const int* in_sizes, int n_in,
                              void* d_out, int out_size, void* d_ws, size_t ws_size,
                              hipStream_t stream) {
  const float* x    = (const float*)d_in[0];
  const float* ng   = (const float*)d_in[1];
  const float* nb   = (const float*)d_in[2];
  const float* Wq   = (const float*)d_in[3];
  const float* Wkv  = (const float*)d_in[4];
  const float* qs   = (const float*)d_in[5];
  const float* ks   = (const float*)d_in[6];
  const float* nkv  = (const float*)d_in[7];
  const float* Wout = (const float*)d_in[8];
  float* out = (float*)d_out;
  char* ws = (char*)d_ws;

  // layout (bytes):
  u16* xn    = (u16*)(ws + 0);            // 8,388,608 (AO reuses after Q-GEMM)
  u16* WoutT = (u16*)(ws + 8388608);      // 2,097,152
  u16* Qn    = (u16*)(ws + 10485760);     // 8,388,608
  u16* Kb    = (u16*)(ws + 18874368);     // 8,650,752 (JP stride)
  u16* VTp   = (u16*)(ws + 27525120);     // 8,650,752
  // overlay region @36175872 (dead by attn time):
  u16* xbf   = (u16*)(ws + 36175872);     // 8,388,608  (dead after KV-GEMM)
  u16* WqT   = (u16*)(ws + 44564480);     // 2,097,152  (dead after Q-GEMM)
  u16* WkvT  = (u16*)(ws + 46661632);     // 4,194,304  (dead after KV-GEMM)
  u16* Vb    = (u16*)(ws + 50855936);     // 8,396,800  (dead after vtransp) end 59,252,736
  u16* parts = xbf;                       // 32*39*16896 = 21,086,208 (fits overlay 23,076,864)
  u16* AO    = xn;

  ktranspose3<<<dim3(128, 32), 256, 0, stream>>>(Wq, Wkv, Wout, WqT, WkvT, WoutT);
  lnorm_k<<<4096, 256, 0, stream>>>(x, ng, nb, xn, xbf);
  gemm_k<2><<<dim3(16, 32), 256, 0, stream>>>(xn, WqT, Qn, nullptr, qs, M_, 1024, 1024);
  gemm_k<3><<<dim3(32, 32), 256, 0, stream>>>(xbf, WkvT, Kb, Vb, ks, M_, 2048, 1024);
  vtransp_k<<<dim3(33, 32), 256, 0, stream>>>(Vb, nkv, ks, Kb, VTp);
  attn_k<<<dim3(NSEG2_, 32), 256, 0, stream>>>(Qn, Kb, VTp, qs, ks, parts);
  comb_k<<<dim3(16, 32), 256, 0, stream>>>(parts, AO);
  gemm_k<1><<<dim3(16, 32), 256, 0, stream>>>(AO, WoutT, out, nullptr, nullptr, M_, 1024, 1024);
}

// Round 8
// 215.044 us; speedup vs baseline: 1.1735x; 1.1735x over previous
//
#include <hip/hip_runtime.h>
#include <hip/hip_bf16.h>
#include <stdint.h>

// Problem constants
#define H_    16
#define N_    2048
#define DIM_  1024
#define DH_   64
#define NN_   2
#define J_    2050     // N + NNULL
#define JP_   2112     // 33*64, padded j (Kb zero tail via vtransp, VTp zero-filled)
#define B_    2
#define M_    4096     // B * N
#define QT2_  16       // 128-row q-tiles
#define NSEG2_ 39      // sum over qt2 of ceil((2*qt2+3)/9)
#define SLOT2_ 8448    // u16s per partial slot: 128*64 O + 256 (=128 fp32 l)

#define S8L_  11.541560327111707f   // 8 * log2(e), folded into Qn at Q-GEMM epilogue
#define LOG2E_ 1.4426950408889634f

typedef unsigned short u16;
typedef unsigned int u32;
typedef short bf16x8 __attribute__((ext_vector_type(8)));
typedef float f32x4 __attribute__((ext_vector_type(4)));

__device__ __forceinline__ u16 f2b(float f) {
  union { float f; unsigned int i; } v; v.f = f;
  unsigned int r = v.i + 0x7fffu + ((v.i >> 16) & 1u);   // RNE
  return (u16)(r >> 16);
}
__device__ __forceinline__ float lo2f(u32 u) {
  union { u32 i; float f; } v; v.i = u << 16; return v.f;
}
__device__ __forceinline__ float hi2f(u32 u) {
  union { u32 i; float f; } v; v.i = u & 0xffff0000u; return v.f;
}
__device__ __forceinline__ void unp8(const uint4 u, float* d) {
  d[0] = lo2f(u.x); d[1] = hi2f(u.x); d[2] = lo2f(u.y); d[3] = hi2f(u.y);
  d[4] = lo2f(u.z); d[5] = hi2f(u.z); d[6] = lo2f(u.w); d[7] = hi2f(u.w);
}
// packed fp32x2 -> bf16x2 (single v_cvt_pk_bf16_f32)
__device__ __forceinline__ u32 pk2(float a, float b) {
  union { __hip_bfloat162 h; u32 u; } x;
  x.h = __float22bfloat162_rn(make_float2(a, b));
  return x.u;
}
// async global->LDS DMA, 16B/lane; LDS dest = wave-uniform base + lane*16
__device__ __forceinline__ void dma16(const u16* g, u16* l) {
  __builtin_amdgcn_global_load_lds(
      (const __attribute__((address_space(1))) u32*)(const void*)g,
      (__attribute__((address_space(3))) u32*)(void*)l, 16, 0, 0);
}

// ------------- fused transpose + cast of the 3 weight matrices -------------
// Wq (1024x1024), Wkv (1024x2048), Wout (1024x1024); fp32 RxC -> bf16 CxR
__global__ __launch_bounds__(256) void ktranspose3(const float* __restrict__ Wq,
                                                   const float* __restrict__ Wkv,
                                                   const float* __restrict__ Wout,
                                                   u16* __restrict__ WqT,
                                                   u16* __restrict__ WkvT,
                                                   u16* __restrict__ WoutT) {
  __shared__ float tile[32][33];
  int bx = blockIdx.x;
  const float* in; u16* out; int C; int cx;
  if (bx < 32)      { in = Wq;   out = WqT;   C = 1024; cx = bx; }
  else if (bx < 96) { in = Wkv;  out = WkvT;  C = 2048; cx = bx - 32; }
  else              { in = Wout; out = WoutT; C = 1024; cx = bx - 96; }
  const int R = 1024;
  int tx = threadIdx.x & 31, ty = threadIdx.x >> 5;   // 32 x 8
  int c0 = cx * 32, r0 = blockIdx.y * 32;
  #pragma unroll
  for (int i = 0; i < 32; i += 8)
    tile[ty + i][tx] = in[(size_t)(r0 + ty + i) * C + c0 + tx];
  __syncthreads();
  #pragma unroll
  for (int i = 0; i < 32; i += 8)
    out[(size_t)(c0 + ty + i) * R + r0 + tx] = f2b(tile[tx][ty + i]);
}

// ---------- LayerNorm (fp32 in) -> xn (bf16 LN) + xbf (bf16 cast of x) ----------
__global__ __launch_bounds__(256) void lnorm_k(const float* __restrict__ x,
                                               const float* __restrict__ g,
                                               const float* __restrict__ bb,
                                               u16* __restrict__ xn,
                                               u16* __restrict__ xbf) {
  int row = blockIdx.x;
  int t = threadIdx.x;
  float4 rw = *(const float4*)(x + (size_t)row * DIM_ + t * 4);
  float v0 = rw.x, v1 = rw.y, v2 = rw.z, v3 = rw.w;
  uint2 cw;
  cw.x = pk2(v0, v1);
  cw.y = pk2(v2, v3);
  *(uint2*)(xbf + (size_t)row * DIM_ + t * 4) = cw;
  float s = v0 + v1 + v2 + v3;
  float ss = v0 * v0 + v1 * v1 + v2 * v2 + v3 * v3;
  #pragma unroll
  for (int o = 32; o; o >>= 1) { s += __shfl_xor(s, o, 64); ss += __shfl_xor(ss, o, 64); }
  __shared__ float red[8];
  int lane = t & 63, w = t >> 6;
  if (lane == 0) { red[w] = s; red[4 + w] = ss; }
  __syncthreads();
  float S = red[0] + red[1] + red[2] + red[3];
  float SS = red[4] + red[5] + red[6] + red[7];
  float mu = S * (1.0f / DIM_);
  float var = SS * (1.0f / DIM_) - mu * mu;
  float rs = rsqrtf(var + 1e-5f);
  float4 gv = *(const float4*)(g + t * 4);
  float4 bv = *(const float4*)(bb + t * 4);
  uint2 ow;
  ow.x = pk2((v0 - mu) * rs * gv.x + bv.x, (v1 - mu) * rs * gv.y + bv.y);
  ow.y = pk2((v2 - mu) * rs * gv.z + bv.z, (v3 - mu) * rs * gv.w + bv.w);
  *(uint2*)(xn + (size_t)row * DIM_ + t * 4) = ow;
}

// ---------------- MFMA GEMM, 128m x 128n tile (m97-style), BK=64, dbuf ----------------
// R7: tile 128x64 -> 128x128, wave decomposition 2x2 (wave = 64x64 sub-tile, acc[4][4]).
//   Rationale: R5's KV-GEMM ran at 379 TF with ~3300cyc/K-step vs ~350cyc compute -- the
//   per-step barrier drain dominates. 128^2 doubles compute under each drain and improves
//   ds_read:MFMA density 0.75 -> 0.5. LDS 64KB dbuf -> 2 blocks/CU (KV grid 512 = exact fit).
//   No __launch_bounds__ cap: ~170 live VGPRs must not spill (R6 lesson).
// LDS slot for (row, kblk of 8 u16): row*64 + ((kblk ^ (row&7)) * 8)  -> conflict-free b128
// MODE 1: fp32 row-major -> dst0
// MODE 2: per-row l2norm over 64-col head * qs * 8*log2e -> Qn (b,h,n,d)
// MODE 3: cols<1024: l2norm*ks -> Kb (stride JP); else bf16 -> Vb (stride J)
// (wave's 64 cols = one head; 128-tiles never straddle col 1024)
template <int MODE>
__global__ __launch_bounds__(256) void gemm_k(const u16* __restrict__ A,
                                              const u16* __restrict__ BT,
                                              void* __restrict__ dst0,
                                              void* __restrict__ dst1,
                                              const float* __restrict__ scale,
                                              int M, int Nc, int K) {
  __shared__ u16 As[2][128 * 64];   // 32 KB
  __shared__ u16 Bs[2][128 * 64];   // 32 KB
  int tid = threadIdx.x, wv = tid >> 6, lane = tid & 63;
  int fm = lane & 15, fg = lane >> 4;
  int fg4 = fg * 4;
  int wr = wv >> 1, wc = wv & 1;           // 2x2 wave grid
  // ---- bijective XCD y-chunk remap (gy=32=8*4, grid%8==0 for all call sites) ----
  int nlin = (int)blockIdx.x + (int)gridDim.x * (int)blockIdx.y;
  int gx = (int)gridDim.x;
  int ypc = (int)gridDim.y >> 3;           // row-panels per XCD (=4)
  int mm = nlin >> 3;
  int row0 = ((nlin & 7) * ypc + mm / gx) * 128;
  int col0 = (mm % gx) * 128;
  f32x4 acc[4][4] = {};
  // staging geometry: one dma16 = 8 rows x 128B; lane i -> row i>>3, stored kblk i&7
  int srow = lane >> 3;                 // 0..7
  int skb = ((lane & 7) ^ srow) * 8;    // swizzled global k-offset (u16)
  const u16* Ag = A + (size_t)(row0 + wv * 32 + srow) * K + skb;
  const u16* Bg = BT + (size_t)(col0 + wv * 32 + srow) * K + skb;
  // frag read offsets (row&7 == fm&7 since row = mult16 + fm)
  int fr7 = fm & 7;
  int ak0 = (fg ^ fr7) * 8;            // k-half 0: kblk = fg
  int ak1 = ((fg + 4) ^ fr7) * 8;      // k-half 1: kblk = fg + 4
  // stage K-step k0 into buffer buf: each wave 32 rows of A and 32 rows of BT
  auto stageg = [&](int k0, int buf) {
    u16* AsW = As[buf] + (wv * 32) * 64;
    u16* BsW = Bs[buf] + (wv * 32) * 64;
    dma16(Ag + k0,                    AsW);
    dma16(Ag + (size_t)8 * K + k0,    AsW + 8 * 64);
    dma16(Ag + (size_t)16 * K + k0,   AsW + 16 * 64);
    dma16(Ag + (size_t)24 * K + k0,   AsW + 24 * 64);
    dma16(Bg + k0,                    BsW);
    dma16(Bg + (size_t)8 * K + k0,    BsW + 8 * 64);
    dma16(Bg + (size_t)16 * K + k0,   BsW + 16 * 64);
    dma16(Bg + (size_t)24 * K + k0,   BsW + 24 * 64);
  };
  // ---- prologue ----
  stageg(0, 0);
  __syncthreads();
  int cur = 0;
  for (int k0 = 0; k0 < K; k0 += 64) {
    if (k0 + 64 < K) stageg(k0 + 64, cur ^ 1);
    // compute current buffer: wave (wr,wc) does 64x64 = 4x4 16x16 tiles, K=64
    bf16x8 af0[4], af1[4], bf0[4], bf1[4];
    #pragma unroll
    for (int mt = 0; mt < 4; mt++) {
      int rbase = (wr * 64 + mt * 16 + fm) * 64;
      af0[mt] = *(const bf16x8*)&As[cur][rbase + ak0];
      af1[mt] = *(const bf16x8*)&As[cur][rbase + ak1];
    }
    #pragma unroll
    for (int nt = 0; nt < 4; nt++) {
      int rbase = (wc * 64 + nt * 16 + fm) * 64;
      bf0[nt] = *(const bf16x8*)&Bs[cur][rbase + ak0];
      bf1[nt] = *(const bf16x8*)&Bs[cur][rbase + ak1];
    }
    #pragma unroll
    for (int mt = 0; mt < 4; mt++)
      #pragma unroll
      for (int nt = 0; nt < 4; nt++) {
        acc[mt][nt] = __builtin_amdgcn_mfma_f32_16x16x32_bf16(af0[mt], bf0[nt], acc[mt][nt], 0, 0, 0);
        acc[mt][nt] = __builtin_amdgcn_mfma_f32_16x16x32_bf16(af1[mt], bf1[nt], acc[mt][nt], 0, 0, 0);
      }
    __syncthreads();
    cur ^= 1;
  }
  // C/D layout per 16x16 tile: col = fm, row = fg*4 + r
  int colw = col0 + wc * 64;            // wave's first col (= one head for MODE 2/3)
  if (MODE == 1) {
    float* C = (float*)dst0;
    #pragma unroll
    for (int mt = 0; mt < 4; mt++)
      #pragma unroll
      for (int r = 0; r < 4; r++) {
        int m = row0 + wr * 64 + mt * 16 + fg4 + r;
        #pragma unroll
        for (int nt = 0; nt < 4; nt++)
          C[(size_t)m * Nc + colw + nt * 16 + fm] = acc[mt][nt][r];
      }
  } else {
    bool isK = (MODE == 2) || (colw < 1024);
    int h = (isK ? colw : colw - 1024) >> 6;
    float sv[4];
    if (isK) {
      #pragma unroll
      for (int nt = 0; nt < 4; nt++) sv[nt] = scale[nt * 16 + fm];
      if (MODE == 2) {
        #pragma unroll
        for (int nt = 0; nt < 4; nt++) sv[nt] *= S8L_;
      }
    }
    u16* Do = (u16*)((MODE == 3 && !isK) ? dst1 : dst0);
    #pragma unroll
    for (int mt = 0; mt < 4; mt++) {
      #pragma unroll
      for (int r = 0; r < 4; r++) {
        float inv = 1.0f;
        if (isK) {
          float ssp = 0.0f;
          #pragma unroll
          for (int nt = 0; nt < 4; nt++) ssp += acc[mt][nt][r] * acc[mt][nt][r];
          #pragma unroll
          for (int o = 1; o <= 8; o <<= 1) ssp += __shfl_xor(ssp, o, 64);
          inv = 1.0f / fmaxf(sqrtf(ssp), 1e-12f);
        }
        int m = row0 + wr * 64 + mt * 16 + fg4 + r;
        int b = m >> 11, n = m & 2047;
        size_t base;
        if (MODE == 2)      base = (((size_t)(b * H_ + h)) * N_ + n) * 64;
        else if (isK)       base = (((size_t)(b * H_ + h)) * JP_ + (n + NN_)) * 64;
        else                base = (((size_t)(b * H_ + h)) * J_ + (n + NN_)) * 64;
        #pragma unroll
        for (int nt = 0; nt < 4; nt++) {
          float val = acc[mt][nt][r];
          if (isK) val = val * inv * sv[nt];
          Do[base + nt * 16 + fm] = f2b(val);
        }
      }
    }
  }
}

// ------- V transpose+permute: Vb (b,h,j,d) + null kv -> VTp (b,h,d,pos); also Kb j<2 -------
// Also zero-fills Kb tail rows j in [J_, JP_).
__global__ __launch_bounds__(256) void vtransp_k(const u16* __restrict__ Vb,
                                                 const float* __restrict__ nkv,
                                                 const float* __restrict__ ks,
                                                 u16* __restrict__ Kb,
                                                 u16* __restrict__ VTp) {
  __shared__ u16 tile[64][80];
  int t = threadIdx.x;
  int c = blockIdx.x, bh = blockIdx.y, h = bh & 15;
  int jl = t >> 2, dc = (t & 3) * 16;
  int j = c * 64 + jl;
  if (j < NN_) {
    float kvv[16];
    float kssp = 0.0f;
    #pragma unroll
    for (int e = 0; e < 16; e++) {
      float vv = nkv[(size_t)(h * 4 + 2 * j + 1) * 64 + dc + e];
      tile[jl][dc + e] = f2b(vv);
      float kv = nkv[(size_t)(h * 4 + 2 * j) * 64 + dc + e];
      kvv[e] = kv; kssp += kv * kv;
    }
    kssp += __shfl_xor(kssp, 1, 64);
    kssp += __shfl_xor(kssp, 2, 64);
    float inv = 1.0f / fmaxf(sqrtf(kssp), 1e-12f);
    #pragma unroll
    for (int e = 0; e < 16; e++)
      Kb[((size_t)bh * JP_ + j) * 64 + dc + e] = f2b(kvv[e] * inv * ks[dc + e]);
  } else if (j < J_) {
    const uint4* src = (const uint4*)(Vb + ((size_t)bh * J_ + j) * 64 + dc);
    *(uint4*)&tile[jl][dc] = src[0];
    *(uint4*)&tile[jl][dc + 8] = src[1];
  } else {
    uint4 z = {0, 0, 0, 0};
    *(uint4*)&tile[jl][dc] = z;
    *(uint4*)&tile[jl][dc + 8] = z;
    uint4* kd = (uint4*)(Kb + ((size_t)bh * JP_ + j) * 64 + dc);
    kd[0] = z;
    kd[1] = z;
  }
  __syncthreads();
  int d = t >> 2, p0 = (t & 3) * 16;
  u16 tmp[16] __attribute__((aligned(16)));
  #pragma unroll
  for (int e = 0; e < 16; e++) {
    int pos = p0 + e;
    int h2 = pos >> 5, rem = pos & 31;
    int fgp = rem >> 3, tt = rem & 7;
    int nt = tt >> 2, r = tt & 3;
    int jloc = (h2 * 2 + nt) * 16 + fgp * 4 + r;
    tmp[e] = tile[jloc][d];
  }
  uint4* dstp = (uint4*)(VTp + ((size_t)bh * 64 + d) * JP_ + c * 64 + p0);
  dstp[0] = ((uint4*)tmp)[0];
  dstp[1] = ((uint4*)tmp)[1];
}

// per-mt softmax: 16 scores -> 16 bf16 P values (8 packed words), lp accumulate
#define SOFTMAX16(ACCS, BSTART, FULLVIS, THR, LP, PW)                                \
  {                                                                                  \
    float bnt = (BSTART);                                                            \
    float lps = 0.0f;                                                                \
    if (FULLVIS) {                                                                   \
      _Pragma("unroll")                                                              \
      for (int nt = 0; nt < 4; nt++) {                                               \
        float e0 = __builtin_amdgcn_exp2f(ACCS[nt][0] + bnt);                        \
        float e1 = __builtin_amdgcn_exp2f((ACCS[nt][1] + sr1) + bnt);                \
        float e2 = __builtin_amdgcn_exp2f((ACCS[nt][2] + sr2) + bnt);                \
        float e3 = __builtin_amdgcn_exp2f((ACCS[nt][3] + sr3) + bnt);                \
        PW[nt * 2] = pk2(e0, e1);                                                    \
        PW[nt * 2 + 1] = pk2(e2, e3);                                                \
        lps += (e0 + e1) + (e2 + e3);                                                \
        bnt += s16;                                                                  \
      }                                                                              \
    } else {                                                                         \
      _Pragma("unroll")                                                              \
      for (int nt = 0; nt < 4; nt++) {                                               \
        int ib = nt * 16 + fg4;                                                      \
        float e0 = __builtin_amdgcn_exp2f(ACCS[nt][0] + bnt);                        \
        float e1 = __builtin_amdgcn_exp2f((ACCS[nt][1] + sr1) + bnt);                \
        float e2 = __builtin_amdgcn_exp2f((ACCS[nt][2] + sr2) + bnt);                \
        float e3 = __builtin_amdgcn_exp2f((ACCS[nt][3] + sr3) + bnt);                \
        e0 = (ib + 0 <= (THR)) ? e0 : 0.0f;                                          \
        e1 = (ib + 1 <= (THR)) ? e1 : 0.0f;                                          \
        e2 = (ib + 2 <= (THR)) ? e2 : 0.0f;                                          \
        e3 = (ib + 3 <= (THR)) ? e3 : 0.0f;                                          \
        PW[nt * 2] = pk2(e0, e1);                                                    \
        PW[nt * 2 + 1] = pk2(e2, e3);                                                \
        lps += (e0 + e1) + (e2 + e3);                                                \
        bnt += s16;                                                                  \
      }                                                                              \
    }                                                                                \
    LP += lps;                                                                       \
  }

// ---------------- MFMA flash attention, 128-row q-tiles, j-SPLIT partials -----
// R5 body EXACTLY (45.3us steady, VGPR 64, no spill). R6's dbuf variant spilled
// (WRITE 165MB) -- intra-block pipelining does not fit this body's register budget
// (confirmed twice: R2, R6). Single-buffered, one barrier pair per chunk.
__global__ __launch_bounds__(256, 4) void attn_k(const u16* __restrict__ Qn,
                                                 const u16* __restrict__ Kb,
                                                 const u16* __restrict__ VTp,
                                                 const float* __restrict__ qs,
                                                 const float* __restrict__ ks,
                                                 u16* __restrict__ partials) {
  __shared__ u16 Ks0[64 * 32], Ks1[64 * 32];   // K chunk rows j, d 0..31 / 32..63
  __shared__ u16 Vs0[64 * 32], Vs1[64 * 32];   // V^T chunk rows d, j-pos 0..31 / 32..63
  int tid = threadIdx.x;
  int wv = tid >> 6, lane = tid & 63;
  int fm = lane & 15, fg = lane >> 4;
  int fg4 = fg * 4;
  // ---- T1 bijective XCD remap ----
  int n = (int)blockIdx.x + NSEG2_ * (int)blockIdx.y;  // hw linear id (x-major)
  int m = n >> 3;                                      // 0..155
  int bh = (n & 7) * 4 + m / NSEG2_;                   // 4 bh per XCD
  int segid = m % NSEG2_;
  int h = bh & 15;
  // segment decode (qt2 descending)
  int cum = 0, qt2 = 0, seg = 0;
  #pragma unroll 1
  for (int i = 0; i < 16; i++) {
    int t = 15 - i, s = (2 * t + 11) / 9;
    if (segid < cum + s) { qt2 = t; seg = segid - cum; break; }
    cum += s;
  }
  int q0 = qt2 * 128;
  int qw = q0 + wv * 32;          // wave's first row (mt=0, fm=0)
  int qr = qw + fm;               // lane's mt=0 row
  float slope = exp2f(-0.5f * (float)(h + 1));
  float prod = fabsf(qs[lane] * ks[lane]);
  #pragma unroll
  for (int o = 32; o; o >>= 1) prod = fmaxf(prod, __shfl_xor(prod, o, 64));
  float MbL = 8.0f * prod * LOG2E_;          // max-bound, log2 domain
  float slopeL = slope * LOG2E_;
  // Q frags: mt0 row qr, mt1 row qr+16
  const u16* qp = Qn + ((size_t)bh * N_ + qr) * 64 + fg * 8;
  bf16x8 qa0 = *(const bf16x8*)(qp);
  bf16x8 qa1 = *(const bf16x8*)(qp + 32);
  bf16x8 qb0 = *(const bf16x8*)(qp + 16 * 64);
  bf16x8 qb1 = *(const bf16x8*)(qp + 16 * 64 + 32);
  f32x4 accO[2][4] = {};
  float lp0 = 0.0f, lp1 = 0.0f;
  int lr = lane >> 2;                                  // staging row 0..15
  int kbs = ((lane & 3) ^ ((lane >> 3) & 3)) * 8;      // swizzled staging k-offset
  int fs = (fg ^ ((fm >> 1) & 3)) * 8;                 // swizzled frag offset
  const u16* KbBH = Kb + (size_t)bh * JP_ * 64;
  const u16* VTbh = VTp + (size_t)bh * 64 * JP_;
  int c0 = seg * 9;
  int c1 = min(c0 + 9, 2 * qt2 + 3);
  // bias ladder (mt0): bias0 at (chunk c0, nt=0, r=0): slopeL*(jj - qr - 2) - MbL
  float bias0 = slopeL * (float)(c0 * 64 + fg4 - qr - 2) - MbL;
  float sr1 = slopeL, sr2 = slopeL * 2.0f, sr3 = slopeL * 3.0f;
  float s16 = slopeL * 16.0f;
  float d64 = slopeL * 64.0f;
  for (int c = c0; c < c1; c++) {
    int jb = c * 64;
    __syncthreads();
    const u16* Kg = KbBH + (size_t)(jb + wv * 16 + lr) * 64 + kbs;
    dma16(Kg,      Ks0 + wv * 512);
    dma16(Kg + 32, Ks1 + wv * 512);
    const u16* Vg = VTbh + (size_t)(wv * 16 + lr) * JP_ + jb + kbs;
    dma16(Vg,      Vs0 + wv * 512);
    dma16(Vg + 32, Vs1 + wv * 512);
    __syncthreads();
    // whole-chunk skip if all 32 wave rows are masked (wave max row qw+31)
    if (jb <= qw + 33) {
      // S^T = K Q^T, both mt share K fragments (Qn pre-scaled by 8*log2e)
      f32x4 accS0[4] = {}, accS1[4] = {};
      #pragma unroll
      for (int nt = 0; nt < 4; nt++) {
        bf16x8 kf0 = *(const bf16x8*)&Ks0[(nt * 16 + fm) * 32 + fs];
        accS0[nt] = __builtin_amdgcn_mfma_f32_16x16x32_bf16(kf0, qa0, accS0[nt], 0, 0, 0);
        accS1[nt] = __builtin_amdgcn_mfma_f32_16x16x32_bf16(kf0, qb0, accS1[nt], 0, 0, 0);
        bf16x8 kf1 = *(const bf16x8*)&Ks1[(nt * 16 + fm) * 32 + fs];
        accS0[nt] = __builtin_amdgcn_mfma_f32_16x16x32_bf16(kf1, qa1, accS0[nt], 0, 0, 0);
        accS1[nt] = __builtin_amdgcn_mfma_f32_16x16x32_bf16(kf1, qb1, accS1[nt], 0, 0, 0);
      }
      // softmax per mt
      union { bf16x8 v[2]; u32 u[8]; } PA, PB;
      bool fv0 = (jb + 61 <= qw);
      bool fv1 = (jb + 61 <= qw + 16);
      int thr0 = qr + 2 - jb;
      SOFTMAX16(accS0, bias0, fv0, thr0, lp0, PA.u);
      SOFTMAX16(accS1, bias0 - s16, fv1, thr0 + 16, lp1, PB.u);
      // O^T += V^T P^T, both mt share V fragments
      #pragma unroll
      for (int nt = 0; nt < 4; nt++) {
        bf16x8 vf0 = *(const bf16x8*)&Vs0[(nt * 16 + fm) * 32 + fs];
        accO[0][nt] = __builtin_amdgcn_mfma_f32_16x16x32_bf16(vf0, PA.v[0], accO[0][nt], 0, 0, 0);
        accO[1][nt] = __builtin_amdgcn_mfma_f32_16x16x32_bf16(vf0, PB.v[0], accO[1][nt], 0, 0, 0);
        bf16x8 vf1 = *(const bf16x8*)&Vs1[(nt * 16 + fm) * 32 + fs];
        accO[0][nt] = __builtin_amdgcn_mfma_f32_16x16x32_bf16(vf1, PA.v[1], accO[0][nt], 0, 0, 0);
        accO[1][nt] = __builtin_amdgcn_mfma_f32_16x16x32_bf16(vf1, PB.v[1], accO[1][nt], 0, 0, 0);
      }
    }
    bias0 += d64;
  }
  lp0 += __shfl_xor(lp0, 16, 64);
  lp0 += __shfl_xor(lp0, 32, 64);
  lp1 += __shfl_xor(lp1, 16, 64);
  lp1 += __shfl_xor(lp1, 32, 64);
  // slot: [q 128][d 64] bf16 + l fp32[128]
  u16* P = partials + ((size_t)bh * NSEG2_ + segid) * SLOT2_;
  #pragma unroll
  for (int mt = 0; mt < 2; mt++) {
    int sq = wv * 32 + mt * 16 + fm;
    #pragma unroll
    for (int nt = 0; nt < 4; nt++) {
      uint2 ow;
      ow.x = pk2(accO[mt][nt][0], accO[mt][nt][1]);
      ow.y = pk2(accO[mt][nt][2], accO[mt][nt][3]);
      *(uint2*)(P + sq * 64 + nt * 16 + fg4) = ow;
    }
    if (fg == 0) *(float*)(P + 8192 + 2 * sq) = (mt == 0) ? lp0 : lp1;
  }
}

// ---------------- combine partials -> AO (b,n,h,d), 128-row tiles ----------------
__global__ __launch_bounds__(256) void comb_k(const u16* __restrict__ partials,
                                              u16* __restrict__ AO) {
  int qt2 = blockIdx.x, bh = blockIdx.y, b = bh >> 4, h = bh & 15;
  int t = threadIdx.x, q = t >> 1, dh = (t & 1) * 32;
  int s = (2 * qt2 + 11) / 9;
  int cum = 0;
  for (int tt = qt2 + 1; tt < 16; tt++) cum += (2 * tt + 11) / 9;
  float acc[32] = {};
  float lsum = 0.0f;
  for (int k = 0; k < s; k++) {
    const u16* P = partials + ((size_t)bh * NSEG2_ + cum + k) * SLOT2_;
    float tmp[8];
    #pragma unroll
    for (int w = 0; w < 4; w++) {
      uint4 a = *(const uint4*)(P + q * 64 + dh + w * 8);
      unp8(a, tmp);
      #pragma unroll
      for (int e = 0; e < 8; e++) acc[w * 8 + e] += tmp[e];
    }
    lsum += *(const float*)(P + 8192 + 2 * q);
  }
  float linv = 1.0f / lsum;
  int nrow = qt2 * 128 + q;
  u16* dst = AO + (((size_t)(b * N_ + nrow)) * H_ + h) * 64 + dh;
  u16 ov[32] __attribute__((aligned(16)));
  #pragma unroll
  for (int e = 0; e < 32; e++) ov[e] = f2b(acc[e] * linv);
  #pragma unroll
  for (int w = 0; w < 4; w++)
    *(uint4*)(dst + w * 8) = ((uint4*)ov)[w];
}

// ---------------- launch ----------------
extern "C" void kernel_launch(void* const* d_in, const int* in_sizes, int n_in,
                              void* d_out, int out_size, void* d_ws, size_t ws_size,
                              hipStream_t stream) {
  const float* x    = (const float*)d_in[0];
  const float* ng   = (const float*)d_in[1];
  const float* nb   = (const float*)d_in[2];
  const float* Wq   = (const float*)d_in[3];
  const float* Wkv  = (const float*)d_in[4];
  const float* qs   = (const float*)d_in[5];
  const float* ks   = (const float*)d_in[6];
  const float* nkv  = (const float*)d_in[7];
  const float* Wout = (const float*)d_in[8];
  float* out = (float*)d_out;
  char* ws = (char*)d_ws;

  // layout (bytes):
  u16* xn    = (u16*)(ws + 0);            // 8,388,608 (AO reuses after Q-GEMM)
  u16* WoutT = (u16*)(ws + 8388608);      // 2,097,152
  u16* Qn    = (u16*)(ws + 10485760);     // 8,388,608
  u16* Kb    = (u16*)(ws + 18874368);     // 8,650,752 (JP stride)
  u16* VTp   = (u16*)(ws + 27525120);     // 8,650,752
  // overlay region @36175872 (dead by attn time):
  u16* xbf   = (u16*)(ws + 36175872);     // 8,388,608  (dead after KV-GEMM)
  u16* WqT   = (u16*)(ws + 44564480);     // 2,097,152  (dead after Q-GEMM)
  u16* WkvT  = (u16*)(ws + 46661632);     // 4,194,304  (dead after KV-GEMM)
  u16* Vb    = (u16*)(ws + 50855936);     // 8,396,800  (dead after vtransp) end 59,252,736
  u16* parts = xbf;                       // 32*39*16896 = 21,086,208 (fits overlay 23,076,864)
  u16* AO    = xn;

  ktranspose3<<<dim3(128, 32), 256, 0, stream>>>(Wq, Wkv, Wout, WqT, WkvT, WoutT);
  lnorm_k<<<4096, 256, 0, stream>>>(x, ng, nb, xn, xbf);
  gemm_k<2><<<dim3(8, 32), 256, 0, stream>>>(xn, WqT, Qn, nullptr, qs, M_, 1024, 1024);
  gemm_k<3><<<dim3(16, 32), 256, 0, stream>>>(xbf, WkvT, Kb, Vb, ks, M_, 2048, 1024);
  vtransp_k<<<dim3(33, 32), 256, 0, stream>>>(Vb, nkv, ks, Kb, VTp);
  attn_k<<<dim3(NSEG2_, 32), 256, 0, stream>>>(Qn, Kb, VTp, qs, ks, parts);
  comb_k<<<dim3(16, 32), 256, 0, stream>>>(parts, AO);
  gemm_k<1><<<dim3(8, 32), 256, 0, stream>>>(AO, WoutT, out, nullptr, nullptr, M_, 1024, 1024);
}

// Round 9
// 211.547 us; speedup vs baseline: 1.1929x; 1.0165x over previous
//
#include <hip/hip_runtime.h>
#include <hip/hip_bf16.h>
#include <stdint.h>

// Problem constants
#define H_    16
#define N_    2048
#define DIM_  1024
#define DH_   64
#define NN_   2
#define J_    2050     // N + NNULL
#define JP_   2112     // 33*64, padded j (tails zeroed in prep)
#define B_    2
#define M_    4096     // B * N
#define NSEG_ 84       // sum over qt of ceil((qt+2)/8)  (64-row q-tiles)

#define S8L_  11.541560327111707f   // 8 * log2(e), folded into Qn at Q-GEMM epilogue
#define LOG2E_ 1.4426950408889634f

typedef unsigned short u16;
typedef unsigned int u32;
typedef short bf16x8 __attribute__((ext_vector_type(8)));
typedef float f32x4 __attribute__((ext_vector_type(4)));

__device__ __forceinline__ u16 f2b(float f) {
  union { float f; unsigned int i; } v; v.f = f;
  unsigned int r = v.i + 0x7fffu + ((v.i >> 16) & 1u);   // RNE
  return (u16)(r >> 16);
}
__device__ __forceinline__ float lo2f(u32 u) {
  union { u32 i; float f; } v; v.i = u << 16; return v.f;
}
__device__ __forceinline__ float hi2f(u32 u) {
  union { u32 i; float f; } v; v.i = u & 0xffff0000u; return v.f;
}
__device__ __forceinline__ void unp8(const uint4 u, float* d) {
  d[0] = lo2f(u.x); d[1] = hi2f(u.x); d[2] = lo2f(u.y); d[3] = hi2f(u.y);
  d[4] = lo2f(u.z); d[5] = hi2f(u.z); d[6] = lo2f(u.w); d[7] = hi2f(u.w);
}
// packed fp32x2 -> bf16x2 (single v_cvt_pk_bf16_f32)
__device__ __forceinline__ u32 pk2(float a, float b) {
  union { __hip_bfloat162 h; u32 u; } x;
  x.h = __float22bfloat162_rn(make_float2(a, b));
  return x.u;
}
// async global->LDS DMA, 16B/lane; LDS dest = wave-uniform base + lane*16
__device__ __forceinline__ void dma16(const u16* g, u16* l) {
  __builtin_amdgcn_global_load_lds(
      (const __attribute__((address_space(1))) u32*)(const void*)g,
      (__attribute__((address_space(3))) u32*)(void*)l, 16, 0, 0);
}

// ---------------- fused prep kernel ----------------
// bx <  128 : transpose+cast Wq/Wkv/Wout (fp32 RxC -> bf16 CxR)
// bx in [128,256): LayerNorm row (bx-128)*32+by -> xn, and bf16 cast -> xbf
// bx == 256 : null-kv rows j<2 -> Kb (l2norm*ks) and VTp (pos=j at c=0)
// bx == 257 : zero Kb rows j in [2048,2112)  (j=2048..2049 overwritten by KV-GEMM later)
// bx == 258 : zero VTp chunk c=32 (pos 0..63; pos 0,1 overwritten by KV-GEMM later)
__global__ __launch_bounds__(256) void prep_k(const float* __restrict__ x,
                                              const float* __restrict__ g,
                                              const float* __restrict__ bb,
                                              const float* __restrict__ Wq,
                                              const float* __restrict__ Wkv,
                                              const float* __restrict__ Wout,
                                              const float* __restrict__ nkv,
                                              const float* __restrict__ ks,
                                              u16* __restrict__ xn,
                                              u16* __restrict__ xbf,
                                              u16* __restrict__ WqT,
                                              u16* __restrict__ WkvT,
                                              u16* __restrict__ WoutT,
                                              u16* __restrict__ Kb,
                                              u16* __restrict__ VTp) {
  __shared__ float tile[32][33];
  __shared__ float red[8];
  int bx = blockIdx.x, by = blockIdx.y;
  int t = threadIdx.x;
  if (bx < 128) {
    // ---- weight transpose+cast ----
    const float* in; u16* out; int C; int cx;
    if (bx < 32)      { in = Wq;   out = WqT;   C = 1024; cx = bx; }
    else if (bx < 96) { in = Wkv;  out = WkvT;  C = 2048; cx = bx - 32; }
    else              { in = Wout; out = WoutT; C = 1024; cx = bx - 96; }
    const int R = 1024;
    int tx = t & 31, ty = t >> 5;   // 32 x 8
    int c0 = cx * 32, r0 = by * 32;
    #pragma unroll
    for (int i = 0; i < 32; i += 8)
      tile[ty + i][tx] = in[(size_t)(r0 + ty + i) * C + c0 + tx];
    __syncthreads();
    #pragma unroll
    for (int i = 0; i < 32; i += 8)
      out[(size_t)(c0 + ty + i) * R + r0 + tx] = f2b(tile[tx][ty + i]);
  } else if (bx < 256) {
    // ---- LayerNorm ----
    int row = (bx - 128) * 32 + by;
    float4 rw = *(const float4*)(x + (size_t)row * DIM_ + t * 4);
    float v0 = rw.x, v1 = rw.y, v2 = rw.z, v3 = rw.w;
    uint2 cw;
    cw.x = pk2(v0, v1);
    cw.y = pk2(v2, v3);
    *(uint2*)(xbf + (size_t)row * DIM_ + t * 4) = cw;
    float s = v0 + v1 + v2 + v3;
    float ss = v0 * v0 + v1 * v1 + v2 * v2 + v3 * v3;
    #pragma unroll
    for (int o = 32; o; o >>= 1) { s += __shfl_xor(s, o, 64); ss += __shfl_xor(ss, o, 64); }
    int lane = t & 63, w = t >> 6;
    if (lane == 0) { red[w] = s; red[4 + w] = ss; }
    __syncthreads();
    float S = red[0] + red[1] + red[2] + red[3];
    float SS = red[4] + red[5] + red[6] + red[7];
    float mu = S * (1.0f / DIM_);
    float var = SS * (1.0f / DIM_) - mu * mu;
    float rs = rsqrtf(var + 1e-5f);
    float4 gv = *(const float4*)(g + t * 4);
    float4 bv = *(const float4*)(bb + t * 4);
    uint2 ow;
    ow.x = pk2((v0 - mu) * rs * gv.x + bv.x, (v1 - mu) * rs * gv.y + bv.y);
    ow.y = pk2((v2 - mu) * rs * gv.z + bv.z, (v3 - mu) * rs * gv.w + bv.w);
    *(uint2*)(xn + (size_t)row * DIM_ + t * 4) = ow;
  } else if (bx == 256) {
    // ---- null kv: j = 0,1 ----
    int bh = by, h = bh & 15;
    if (t < 128) {
      int j = t >> 6, d = t & 63;
      float kv = nkv[(size_t)(h * 4 + 2 * j) * 64 + d];
      float vv = nkv[(size_t)(h * 4 + 2 * j + 1) * 64 + d];
      float ssp = kv * kv;
      #pragma unroll
      for (int o = 32; o; o >>= 1) ssp += __shfl_xor(ssp, o, 64);
      float inv = 1.0f / fmaxf(sqrtf(ssp), 1e-12f);
      Kb[((size_t)bh * JP_ + j) * 64 + d] = f2b(kv * inv * ks[d]);
      // VTp: c=0, pos = j for j<2 (pi^{-1}(0)=0, pi^{-1}(1)=1)
      VTp[((size_t)bh * 64 + d) * JP_ + j] = f2b(vv);
    }
  } else if (bx == 257) {
    // ---- zero Kb rows j in [2048, 2112): 64 rows x 64 d = 4096 u16 ----
    int bh = by;
    uint4 z = {0, 0, 0, 0};
    // t*16 u16 each: 256*16 = 4096
    u16* dst = Kb + ((size_t)bh * JP_ + 2048) * 64 + t * 16;
    ((uint4*)dst)[0] = z;
    ((uint4*)dst)[1] = z;
  } else {
    // ---- zero VTp chunk c=32: 64 d-rows x 64 pos = 4096 u16 ----
    int bh = by;
    uint4 z = {0, 0, 0, 0};
    int d = t >> 2, p0 = (t & 3) * 16;
    u16* dst = VTp + ((size_t)bh * 64 + d) * JP_ + 2048 + p0;
    ((uint4*)dst)[0] = z;
    ((uint4*)dst)[1] = z;
  }
}

// ---------------- MFMA GEMM, 128m x 128n tile (m97-style), BK=64, dbuf ----------------
// R7 structure: 2x2 wave grid, wave = 64x64 sub-tile, acc[4][4], 64KB LDS dbuf,
//   XCD y-chunk remap. R8: MODE 3's V branch writes DIRECTLY into VTp (permuted
//   layout) -- replaces the vtransp kernel and the Vb round-trip.
//   pos(jl) = (jl>>5)*32 + ((jl>>2)&3)*8 + ((jl>>4)&1)*4 + (jl&3)   [pi inverse]
// LDS slot for (row, kblk of 8 u16): row*64 + ((kblk ^ (row&7)) * 8)
// MODE 1: fp32 row-major -> dst0
// MODE 2: per-row l2norm over 64-col head * qs * 8*log2e -> Qn (b,h,n,d)
// MODE 3: cols<1024: l2norm*ks -> Kb (stride JP); else -> VTp (b,h,d,pos)
template <int MODE>
__global__ __launch_bounds__(256) void gemm_k(const u16* __restrict__ A,
                                              const u16* __restrict__ BT,
                                              void* __restrict__ dst0,
                                              void* __restrict__ dst1,
                                              const float* __restrict__ scale,
                                              int M, int Nc, int K) {
  __shared__ u16 As[2][128 * 64];   // 32 KB
  __shared__ u16 Bs[2][128 * 64];   // 32 KB
  int tid = threadIdx.x, wv = tid >> 6, lane = tid & 63;
  int fm = lane & 15, fg = lane >> 4;
  int fg4 = fg * 4;
  int wr = wv >> 1, wc = wv & 1;           // 2x2 wave grid
  // ---- bijective XCD y-chunk remap (gy=32=8*4) ----
  int nlin = (int)blockIdx.x + (int)gridDim.x * (int)blockIdx.y;
  int gx = (int)gridDim.x;
  int ypc = (int)gridDim.y >> 3;           // row-panels per XCD (=4)
  int mm = nlin >> 3;
  int row0 = ((nlin & 7) * ypc + mm / gx) * 128;
  int col0 = (mm % gx) * 128;
  f32x4 acc[4][4] = {};
  // staging geometry: one dma16 = 8 rows x 128B; lane i -> row i>>3, stored kblk i&7
  int srow = lane >> 3;                 // 0..7
  int skb = ((lane & 7) ^ srow) * 8;    // swizzled global k-offset (u16)
  const u16* Ag = A + (size_t)(row0 + wv * 32 + srow) * K + skb;
  const u16* Bg = BT + (size_t)(col0 + wv * 32 + srow) * K + skb;
  // frag read offsets (row&7 == fm&7 since row = mult16 + fm)
  int fr7 = fm & 7;
  int ak0 = (fg ^ fr7) * 8;            // k-half 0: kblk = fg
  int ak1 = ((fg + 4) ^ fr7) * 8;      // k-half 1: kblk = fg + 4
  auto stageg = [&](int k0, int buf) {
    u16* AsW = As[buf] + (wv * 32) * 64;
    u16* BsW = Bs[buf] + (wv * 32) * 64;
    dma16(Ag + k0,                    AsW);
    dma16(Ag + (size_t)8 * K + k0,    AsW + 8 * 64);
    dma16(Ag + (size_t)16 * K + k0,   AsW + 16 * 64);
    dma16(Ag + (size_t)24 * K + k0,   AsW + 24 * 64);
    dma16(Bg + k0,                    BsW);
    dma16(Bg + (size_t)8 * K + k0,    BsW + 8 * 64);
    dma16(Bg + (size_t)16 * K + k0,   BsW + 16 * 64);
    dma16(Bg + (size_t)24 * K + k0,   BsW + 24 * 64);
  };
  stageg(0, 0);
  __syncthreads();
  int cur = 0;
  for (int k0 = 0; k0 < K; k0 += 64) {
    if (k0 + 64 < K) stageg(k0 + 64, cur ^ 1);
    bf16x8 af0[4], af1[4], bf0[4], bf1[4];
    #pragma unroll
    for (int mt = 0; mt < 4; mt++) {
      int rbase = (wr * 64 + mt * 16 + fm) * 64;
      af0[mt] = *(const bf16x8*)&As[cur][rbase + ak0];
      af1[mt] = *(const bf16x8*)&As[cur][rbase + ak1];
    }
    #pragma unroll
    for (int nt = 0; nt < 4; nt++) {
      int rbase = (wc * 64 + nt * 16 + fm) * 64;
      bf0[nt] = *(const bf16x8*)&Bs[cur][rbase + ak0];
      bf1[nt] = *(const bf16x8*)&Bs[cur][rbase + ak1];
    }
    #pragma unroll
    for (int mt = 0; mt < 4; mt++)
      #pragma unroll
      for (int nt = 0; nt < 4; nt++) {
        acc[mt][nt] = __builtin_amdgcn_mfma_f32_16x16x32_bf16(af0[mt], bf0[nt], acc[mt][nt], 0, 0, 0);
        acc[mt][nt] = __builtin_amdgcn_mfma_f32_16x16x32_bf16(af1[mt], bf1[nt], acc[mt][nt], 0, 0, 0);
      }
    __syncthreads();
    cur ^= 1;
  }
  // C/D layout per 16x16 tile: col = fm, row = fg*4 + r
  int colw = col0 + wc * 64;            // wave's first col (= one head for MODE 2/3)
  if (MODE == 1) {
    float* C = (float*)dst0;
    #pragma unroll
    for (int mt = 0; mt < 4; mt++)
      #pragma unroll
      for (int r = 0; r < 4; r++) {
        int m = row0 + wr * 64 + mt * 16 + fg4 + r;
        #pragma unroll
        for (int nt = 0; nt < 4; nt++)
          C[(size_t)m * Nc + colw + nt * 16 + fm] = acc[mt][nt][r];
      }
  } else {
    bool isK = (MODE == 2) || (colw < 1024);
    int h = (isK ? colw : colw - 1024) >> 6;
    if (isK) {
      float sv[4];
      #pragma unroll
      for (int nt = 0; nt < 4; nt++) sv[nt] = scale[nt * 16 + fm];
      if (MODE == 2) {
        #pragma unroll
        for (int nt = 0; nt < 4; nt++) sv[nt] *= S8L_;
      }
      u16* Do = (u16*)dst0;
      #pragma unroll
      for (int mt = 0; mt < 4; mt++) {
        #pragma unroll
        for (int r = 0; r < 4; r++) {
          float ssp = 0.0f;
          #pragma unroll
          for (int nt = 0; nt < 4; nt++) ssp += acc[mt][nt][r] * acc[mt][nt][r];
          #pragma unroll
          for (int o = 1; o <= 8; o <<= 1) ssp += __shfl_xor(ssp, o, 64);
          float inv = 1.0f / fmaxf(sqrtf(ssp), 1e-12f);
          int m = row0 + wr * 64 + mt * 16 + fg4 + r;
          int b = m >> 11, n = m & 2047;
          size_t base;
          if (MODE == 2) base = (((size_t)(b * H_ + h)) * N_ + n) * 64;
          else           base = (((size_t)(b * H_ + h)) * JP_ + (n + NN_)) * 64;
          #pragma unroll
          for (int nt = 0; nt < 4; nt++)
            Do[base + nt * 16 + fm] = f2b(acc[mt][nt][r] * inv * sv[nt]);
        }
      }
    } else {
      // V -> VTp directly (permuted): VTp[(bh*64 + d)*JP + c*64 + pos(jl)]
      u16* Do = (u16*)dst1;
      #pragma unroll
      for (int mt = 0; mt < 4; mt++) {
        #pragma unroll
        for (int r = 0; r < 4; r++) {
          int m = row0 + wr * 64 + mt * 16 + fg4 + r;
          int b = m >> 11, n = m & 2047;
          int j = n + NN_;
          int c2 = j >> 6, jl = j & 63;
          int rem = jl & 31;
          int pos = (jl >> 5) * 32 + ((rem >> 2) & 3) * 8 + (rem >> 4) * 4 + (rem & 3);
          size_t hb = (size_t)(b * H_ + h) * 64;
          int off = c2 * 64 + pos;
          #pragma unroll
          for (int nt = 0; nt < 4; nt++)
            Do[(hb + nt * 16 + fm) * JP_ + off] = f2b(acc[mt][nt][r]);
        }
      }
    }
  }
}

// ---------------- MFMA flash attention, 64-row q-tiles (R3 exact, best measured) -----
// j-SPLIT partial blocks, single-buffered, T1 bijective XCD remap
// (xcd=n&7, m=n>>3, bh=xcd*4+m/NSEG, seg=m%NSEG; grid 84x32=2688=8*336).
// Softmax: Qn pre-scaled by 8*log2e; running-scalar bias ladder; exp2 direct;
//   immediate pk2 packing; causal cndmask only on diagonal chunks.
// LDS slot for (row, kblk of 8 u16, 4 kblks/row): row*32 + ((kblk ^ ((row>>1)&3)) * 8)
__global__ __launch_bounds__(256, 6) void attn_k(const u16* __restrict__ Qn,
                                                 const u16* __restrict__ Kb,
                                                 const u16* __restrict__ VTp,
                                                 const float* __restrict__ qs,
                                                 const float* __restrict__ ks,
                                                 u16* __restrict__ partials) {
  __shared__ u16 Ks0[64 * 32], Ks1[64 * 32];   // K chunk rows j, d 0..31 / 32..63
  __shared__ u16 Vs0[64 * 32], Vs1[64 * 32];   // V^T chunk rows d, j-pos 0..31 / 32..63
  int tid = threadIdx.x;
  int wv = tid >> 6, lane = tid & 63;
  int fm = lane & 15, fg = lane >> 4;
  // ---- T1 bijective XCD remap ----
  int n = (int)blockIdx.x + NSEG_ * (int)blockIdx.y;   // hw linear id (x-major)
  int m = n >> 3;                                      // 0..335
  int bh = (n & 7) * 4 + m / NSEG_;                    // 4 bh per XCD
  int segid = m % NSEG_;                               // segment within bh
  int h = bh & 15;
  // segment decode (qt descending)
  int cum = 0, qt = 0, seg = 0;
  #pragma unroll 1
  for (int i = 0; i < 32; i++) {
    int t = 31 - i, s = (t + 9) >> 3;
    if (segid < cum + s) { qt = t; seg = segid - cum; break; }
    cum += s;
  }
  int q0 = qt * 64;
  int q = q0 + wv * 16 + fm;
  float slope = exp2f(-0.5f * (float)(h + 1));
  float prod = fabsf(qs[lane] * ks[lane]);
  #pragma unroll
  for (int o = 32; o; o >>= 1) prod = fmaxf(prod, __shfl_xor(prod, o, 64));
  float MbL = 8.0f * prod * LOG2E_;          // max-bound, in log2 domain
  float slopeL = slope * LOG2E_;
  const u16* qp = Qn + ((size_t)bh * N_ + q) * 64 + fg * 8;
  bf16x8 qf0 = *(const bf16x8*)(qp);        // d 0..31 slice
  bf16x8 qf1 = *(const bf16x8*)(qp + 32);   // d 32..63 slice
  f32x4 accO[4] = {};
  float lp = 0.0f;
  int lr = lane >> 2;                                  // staging row 0..15
  int kbs = ((lane & 3) ^ ((lane >> 3) & 3)) * 8;      // swizzled staging k-offset
  int fs = (fg ^ ((fm >> 1) & 3)) * 8;                 // swizzled frag offset
  const u16* KbBH = Kb + (size_t)bh * JP_ * 64;
  const u16* VTbh = VTp + (size_t)bh * 64 * JP_;
  int c0 = seg * 8;
  int c1 = min(c0 + 8, qt + 2);
  // running bias scalars (log2 domain): bias0 at (chunk start, nt=0, r=0)
  float bias0 = slopeL * (float)(c0 * 64 + fg * 4 - q - 2) - MbL;
  float sr1 = slopeL, sr2 = slopeL * 2.0f, sr3 = slopeL * 3.0f;
  float s16 = slopeL * 16.0f;
  float d64 = slopeL * 64.0f;
  for (int c = c0; c < c1; c++) {
    int jb = c * 64;
    __syncthreads();
    const u16* Kg = KbBH + (size_t)(jb + wv * 16 + lr) * 64 + kbs;
    dma16(Kg,      Ks0 + wv * 512);
    dma16(Kg + 32, Ks1 + wv * 512);
    const u16* Vg = VTbh + (size_t)(wv * 16 + lr) * JP_ + jb + kbs;
    dma16(Vg,      Vs0 + wv * 512);
    dma16(Vg + 32, Vs1 + wv * 512);
    __syncthreads();
    // S^T = K Q^T  (Qn pre-scaled by 8*log2e)
    f32x4 accS[4] = {};
    #pragma unroll
    for (int nt = 0; nt < 4; nt++) {
      bf16x8 kf0 = *(const bf16x8*)&Ks0[(nt * 16 + fm) * 32 + fs];
      accS[nt] = __builtin_amdgcn_mfma_f32_16x16x32_bf16(kf0, qf0, accS[nt], 0, 0, 0);
      bf16x8 kf1 = *(const bf16x8*)&Ks1[(nt * 16 + fm) * 32 + fs];
      accS[nt] = __builtin_amdgcn_mfma_f32_16x16x32_bf16(kf1, qf1, accS[nt], 0, 0, 0);
    }
    // softmax in-register; pack P^T B-frags immediately (<=6 temps live)
    union { bf16x8 v; u32 u[4]; } P0, P1;
    float lps = 0.0f;
    float bnt = bias0;
    if (c < qt) {
      #pragma unroll
      for (int nt = 0; nt < 4; nt++) {
        float e0 = __builtin_amdgcn_exp2f(accS[nt][0] + bnt);
        float e1 = __builtin_amdgcn_exp2f((accS[nt][1] + sr1) + bnt);
        float e2 = __builtin_amdgcn_exp2f((accS[nt][2] + sr2) + bnt);
        float e3 = __builtin_amdgcn_exp2f((accS[nt][3] + sr3) + bnt);
        u32 w0 = pk2(e0, e1);
        u32 w1 = pk2(e2, e3);
        lps += (e0 + e1) + (e2 + e3);
        if (nt < 2) { P0.u[nt * 2] = w0; P0.u[nt * 2 + 1] = w1; }
        else        { P1.u[(nt - 2) * 2] = w0; P1.u[(nt - 2) * 2 + 1] = w1; }
        bnt += s16;
      }
    } else {
      // diagonal chunk: per-element causal mask (idx <= thr  <=>  jj <= q+2)
      int thr = q + 2 - jb;
      #pragma unroll
      for (int nt = 0; nt < 4; nt++) {
        int ib = nt * 16 + fg * 4;
        float e0 = __builtin_amdgcn_exp2f(accS[nt][0] + bnt);
        float e1 = __builtin_amdgcn_exp2f((accS[nt][1] + sr1) + bnt);
        float e2 = __builtin_amdgcn_exp2f((accS[nt][2] + sr2) + bnt);
        float e3 = __builtin_amdgcn_exp2f((accS[nt][3] + sr3) + bnt);
        e0 = (ib + 0 <= thr) ? e0 : 0.0f;
        e1 = (ib + 1 <= thr) ? e1 : 0.0f;
        e2 = (ib + 2 <= thr) ? e2 : 0.0f;
        e3 = (ib + 3 <= thr) ? e3 : 0.0f;
        u32 w0 = pk2(e0, e1);
        u32 w1 = pk2(e2, e3);
        lps += (e0 + e1) + (e2 + e3);
        if (nt < 2) { P0.u[nt * 2] = w0; P0.u[nt * 2 + 1] = w1; }
        else        { P1.u[(nt - 2) * 2] = w0; P1.u[(nt - 2) * 2 + 1] = w1; }
        bnt += s16;
      }
    }
    lp += lps;
    bias0 += d64;
    // O^T += V^T P^T
    #pragma unroll
    for (int nt = 0; nt < 4; nt++) {
      bf16x8 vf0 = *(const bf16x8*)&Vs0[(nt * 16 + fm) * 32 + fs];
      accO[nt] = __builtin_amdgcn_mfma_f32_16x16x32_bf16(vf0, P0.v, accO[nt], 0, 0, 0);
      bf16x8 vf1 = *(const bf16x8*)&Vs1[(nt * 16 + fm) * 32 + fs];
      accO[nt] = __builtin_amdgcn_mfma_f32_16x16x32_bf16(vf1, P1.v, accO[nt], 0, 0, 0);
    }
  }
  lp += __shfl_xor(lp, 16, 64);
  lp += __shfl_xor(lp, 32, 64);
  // slot: [q 64][d 64] bf16 + l fp32[64]
  u16* P = partials + ((size_t)bh * NSEG_ + segid) * 4224;
  int sq = wv * 16 + fm;
  #pragma unroll
  for (int nt = 0; nt < 4; nt++) {
    uint2 ow;
    ow.x = pk2(accO[nt][0], accO[nt][1]);
    ow.y = pk2(accO[nt][2], accO[nt][3]);
    *(uint2*)(P + sq * 64 + nt * 16 + fg * 4) = ow;
  }
  if (fg == 0) *(float*)(P + 4096 + 2 * sq) = lp;
}

// ---------------- combine partials -> AO (b,n,h,d), 64-row tiles (R3) ----------------
__global__ __launch_bounds__(256) void comb_k(const u16* __restrict__ partials,
                                              u16* __restrict__ AO) {
  int qt = blockIdx.x, bh = blockIdx.y, b = bh >> 4, h = bh & 15;
  int t = threadIdx.x, q = t >> 2, dq = (t & 3) * 16;
  int s = (qt + 9) >> 3;
  int cum = 0;
  for (int tt = qt + 1; tt < 32; tt++) cum += (tt + 9) >> 3;
  float acc[16] = {};
  float lsum = 0.0f;
  for (int k = 0; k < s; k++) {
    const u16* P = partials + ((size_t)bh * NSEG_ + cum + k) * 4224;
    uint4 a = *(const uint4*)(P + q * 64 + dq);
    uint4 bq = *(const uint4*)(P + q * 64 + dq + 8);
    float tmp[8];
    unp8(a, tmp);
    #pragma unroll
    for (int e = 0; e < 8; e++) acc[e] += tmp[e];
    unp8(bq, tmp);
    #pragma unroll
    for (int e = 0; e < 8; e++) acc[8 + e] += tmp[e];
    lsum += *(const float*)(P + 4096 + 2 * q);
  }
  float linv = 1.0f / lsum;
  int n = qt * 64 + q;
  u16* dst = AO + (((size_t)(b * N_ + n)) * H_ + h) * 64 + dq;
  u16 ov[16] __attribute__((aligned(16)));
  #pragma unroll
  for (int e = 0; e < 16; e++) ov[e] = f2b(acc[e] * linv);
  *(uint4*)dst = ((uint4*)ov)[0];
  *(uint4*)(dst + 8) = ((uint4*)ov)[1];
}

// ---------------- launch ----------------
extern "C" void kernel_launch(void* const* d_in, const int* in_sizes, int n_in,
                              void* d_out, int out_size, void* d_ws, size_t ws_size,
                              hipStream_t stream) {
  const float* x    = (const float*)d_in[0];
  const float* ng   = (const float*)d_in[1];
  const float* nb   = (const float*)d_in[2];
  const float* Wq   = (const float*)d_in[3];
  const float* Wkv  = (const float*)d_in[4];
  const float* qs   = (const float*)d_in[5];
  const float* ks   = (const float*)d_in[6];
  const float* nkv  = (const float*)d_in[7];
  const float* Wout = (const float*)d_in[8];
  float* out = (float*)d_out;
  char* ws = (char*)d_ws;

  // layout (bytes):
  u16* xn    = (u16*)(ws + 0);            // 8,388,608 (AO reuses after Q-GEMM)
  u16* WoutT = (u16*)(ws + 8388608);      // 2,097,152
  u16* Qn    = (u16*)(ws + 10485760);     // 8,388,608
  u16* Kb    = (u16*)(ws + 18874368);     // 8,650,752 (JP stride)
  u16* VTp   = (u16*)(ws + 27525120);     // 8,650,752
  // overlay region @36175872 (dead by attn time):
  u16* xbf   = (u16*)(ws + 36175872);     // 8,388,608  (dead after KV-GEMM)
  u16* WqT   = (u16*)(ws + 44564480);     // 2,097,152  (dead after Q-GEMM)
  u16* WkvT  = (u16*)(ws + 46661632);     // 4,194,304  (dead after KV-GEMM)
  u16* parts = xbf;                       // 32*84*8448 = 22,708,224 (fits overlay)
  u16* AO    = xn;

  prep_k<<<dim3(259, 32), 256, 0, stream>>>(x, ng, nb, Wq, Wkv, Wout, nkv, ks,
                                            xn, xbf, WqT, WkvT, WoutT, Kb, VTp);
  gemm_k<2><<<dim3(8, 32), 256, 0, stream>>>(xn, WqT, Qn, nullptr, qs, M_, 1024, 1024);
  gemm_k<3><<<dim3(16, 32), 256, 0, stream>>>(xbf, WkvT, Kb, VTp, ks, M_, 2048, 1024);
  attn_k<<<dim3(NSEG_, 32), 256, 0, stream>>>(Qn, Kb, VTp, qs, ks, parts);
  comb_k<<<dim3(32, 32), 256, 0, stream>>>(parts, AO);
  gemm_k<1><<<dim3(8, 32), 256, 0, stream>>>(AO, WoutT, out, nullptr, nullptr, M_, 1024, 1024);
}